// Round 7
// baseline (532.741 us; speedup 1.0000x reference)
//
#include <hip/hip_runtime.h>
#include <hip/hip_bf16.h>
#include <cstddef>
#include <cstdint>

// Problem constants (fixed by the reference setup)
#define N_B   8
#define L_L   4096
#define S_S   4096
#define H_H   8
#define D_D   64
#define NH    64          // N_B * H_H
// KV_aug layout (d-major): rows 0..63 = KV[d][v] (stride 68, cols 64..67 pad),
// row 64 = K_sum[d] (indexed by d in cols 0..63). KVSZ floats per (n,h).
#define KVLD  68
#define KVSZ  (65 * KVLD)   // 4420

__device__ __forceinline__ float elu1(float x) {
    // elu(x)+1 : x>0 ? x+1 : exp(x)
    return x > 0.f ? x + 1.f : __expf(x);
}

// ---------------------------------------------------------------------------
// Phase 1 (v2): per (n,h, s-chunk) block computes partial KV_aug[65][68].
//  v1 diagnosis: 72us vs ~16us floors, VALU 27%, HBM 18%, Occ 35% ->
//  latency-bound on single-buffered staging (per-tile HBM latency serialized
//  with compute by the two barriers).
//  v2: double-buffered LDS + async reg-staging, ONE barrier per tile:
//    barrier -> issue loads(t+1)->regs -> compute(t, buf) -> elu+write buf^1.
//  Writes always hit the opposite buffer => no cross-wave hazard; load
//  latency hides under the 512-FMA compute. Epilogue sAcc overlaid on the
//  staging buffers (union) keeps LDS at 33KB -> 4 blocks/CU.
// ---------------------------------------------------------------------------
__global__ __launch_bounds__(256, 4)
void la_phase1(const float* __restrict__ Kin, const float* __restrict__ Vin,
               float* __restrict__ partials, int split, int schunk)
{
    __shared__ union {
        struct { float K[2][32 * 64]; float V[2][32 * 64]; } st; // 32 KB
        float acc[64 * 68];                                      // 17.3 KB
    } sm;
    __shared__ float sKsumP[4 * 64];     // per-wave ksum partials

    const int b     = blockIdx.x;
    const int nh    = b / split;
    const int chunk = b - nh * split;
    const int n     = nh >> 3;
    const int h     = nh & 7;
    const int s0    = chunk * schunk;

    const int tid  = threadIdx.x;
    const int w    = tid >> 6;
    const int lane = tid & 63;
    const int dg   = lane >> 3;   // d-group: d = dg*8 + i
    const int vg   = lane & 7;    // v-group: v = vg*8 + j

    float acc[8][8];
    #pragma unroll
    for (int i = 0; i < 8; ++i)
        #pragma unroll
        for (int j = 0; j < 8; ++j) acc[i][j] = 0.f;
    float ksum = 0.f;

    // staging map: 256 threads cover 32 rows x 64 cols, 8 floats each
    const int sr = tid >> 3;          // 0..31
    const int sc = (tid & 7) * 8;     // 0,8,...,56
    const int kd = lane;              // ksum d index (per-wave full coverage)

    const float* Kb = Kin + (size_t)n * S_S * (H_H * D_D) + h * D_D;
    const float* Vb = Vin + (size_t)n * S_S * (H_H * D_D) + h * D_D;

    const int ntiles = schunk >> 5;   // tiles of 32 s-rows

    // ---- prologue: stage tile 0 into buf 0 ----
    {
        const float* kg = Kb + (size_t)(s0 + sr) * (H_H * D_D) + sc;
        const float* vp = Vb + (size_t)(s0 + sr) * (H_H * D_D) + sc;
        float4 ka = *(const float4*)kg;
        float4 kc = *(const float4*)(kg + 4);
        float4 va = *(const float4*)vp;
        float4 vc = *(const float4*)(vp + 4);
        ka.x = elu1(ka.x); ka.y = elu1(ka.y); ka.z = elu1(ka.z); ka.w = elu1(ka.w);
        kc.x = elu1(kc.x); kc.y = elu1(kc.y); kc.z = elu1(kc.z); kc.w = elu1(kc.w);
        *(float4*)&sm.st.K[0][sr * 64 + sc]     = ka;
        *(float4*)&sm.st.K[0][sr * 64 + sc + 4] = kc;
        *(float4*)&sm.st.V[0][sr * 64 + sc]     = va;
        *(float4*)&sm.st.V[0][sr * 64 + sc + 4] = vc;
    }

    for (int t = 0; t < ntiles; ++t) {
        const int buf = t & 1;
        __syncthreads();               // buf's staged writes visible

        // issue next tile's loads (in flight across the compute below)
        float4 ka, kc, va, vc;
        const bool more = (t + 1 < ntiles);
        if (more) {
            const int srow = s0 + (t + 1) * 32;
            const float* kg = Kb + (size_t)(srow + sr) * (H_H * D_D) + sc;
            const float* vp = Vb + (size_t)(srow + sr) * (H_H * D_D) + sc;
            ka = *(const float4*)kg;
            kc = *(const float4*)(kg + 4);
            va = *(const float4*)vp;
            vc = *(const float4*)(vp + 4);
        }

        const float* sKb = sm.st.K[buf];
        const float* sVb = sm.st.V[buf];

        // wave w handles s-local rows w*8 .. w*8+7
        #pragma unroll
        for (int sl = 0; sl < 8; ++sl) {
            const int s = w * 8 + sl;
            const float4 k0 = *(const float4*)&sKb[s * 64 + dg * 8];
            const float4 k1 = *(const float4*)&sKb[s * 64 + dg * 8 + 4];
            const float4 v0 = *(const float4*)&sVb[s * 64 + vg * 8];
            const float4 v1 = *(const float4*)&sVb[s * 64 + vg * 8 + 4];
            const float kf[8] = {k0.x, k0.y, k0.z, k0.w, k1.x, k1.y, k1.z, k1.w};
            const float vf[8] = {v0.x, v0.y, v0.z, v0.w, v1.x, v1.y, v1.z, v1.w};
            #pragma unroll
            for (int i = 0; i < 8; ++i)
                #pragma unroll
                for (int j = 0; j < 8; ++j)
                    acc[i][j] = fmaf(kf[i], vf[j], acc[i][j]);
        }
        // K_sum partial over the same 8 rows this wave consumed
        #pragma unroll
        for (int sl = 0; sl < 8; ++sl)
            ksum += sKb[(w * 8 + sl) * 64 + kd];

        // store staged tile t+1 into the OTHER buffer (no hazard with slow
        // waves still computing tile t from buf)
        if (more) {
            ka.x = elu1(ka.x); ka.y = elu1(ka.y); ka.z = elu1(ka.z); ka.w = elu1(ka.w);
            kc.x = elu1(kc.x); kc.y = elu1(kc.y); kc.z = elu1(kc.z); kc.w = elu1(kc.w);
            float* dK = sm.st.K[buf ^ 1];
            float* dV = sm.st.V[buf ^ 1];
            *(float4*)&dK[sr * 64 + sc]     = ka;
            *(float4*)&dK[sr * 64 + sc + 4] = kc;
            *(float4*)&dV[sr * 64 + sc]     = va;
            *(float4*)&dV[sr * 64 + sc + 4] = vc;
        }
    }
    __syncthreads();   // all compute reads done; staging buffers now reusable

    // cross-wave reduce of acc into sm.acc[d][v] (stride 68), sequential & exact
    for (int ww = 0; ww < 4; ++ww) {
        if (w == ww) {
            #pragma unroll
            for (int i = 0; i < 8; ++i) {
                float* p = &sm.acc[(dg * 8 + i) * 68 + vg * 8];
                if (ww == 0) {
                    *(float4*)p       = make_float4(acc[i][0], acc[i][1], acc[i][2], acc[i][3]);
                    *(float4*)(p + 4) = make_float4(acc[i][4], acc[i][5], acc[i][6], acc[i][7]);
                } else {
                    float4 a0 = *(const float4*)p;
                    float4 a1 = *(const float4*)(p + 4);
                    a0.x += acc[i][0]; a0.y += acc[i][1]; a0.z += acc[i][2]; a0.w += acc[i][3];
                    a1.x += acc[i][4]; a1.y += acc[i][5]; a1.z += acc[i][6]; a1.w += acc[i][7];
                    *(float4*)p       = a0;
                    *(float4*)(p + 4) = a1;
                }
            }
        }
        __syncthreads();
    }

    // ksum: deterministic 4-way reduce (one slot per (wave, d))
    sKsumP[w * 64 + kd] = ksum;
    __syncthreads();

    // write this block's partial KV_aug[65][68] d-major (row 64 = K_sum, pads 0)
    float* outp = partials + (size_t)b * KVSZ;
    for (int idx = tid; idx < KVSZ; idx += 256) {
        const int r = idx / KVLD;
        const int c = idx - r * KVLD;
        float val = 0.f;
        if (c < 64) {
            if (r < 64)
                val = sm.acc[idx];   // sm.acc is [d][v] stride 68 == same layout
            else
                val = sKsumP[c] + sKsumP[64 + c] + sKsumP[128 + c] + sKsumP[192 + c];
        }
        outp[idx] = val;
    }
}

// ---------------------------------------------------------------------------
// Reduce: sum the `split` partials per (n,h) -> kvt[nh][65][68]
// ---------------------------------------------------------------------------
__global__ __launch_bounds__(256)
void la_reduce(const float* __restrict__ partials, float* __restrict__ kvt, int split)
{
    const int idx = blockIdx.x * 256 + threadIdx.x;
    if (idx >= NH * KVSZ) return;
    const int nh  = idx / KVSZ;
    const int rem = idx - nh * KVSZ;
    const float* p = partials + (size_t)nh * split * KVSZ + rem;
    float s = 0.f;
    for (int c = 0; c < split; ++c) s += p[(size_t)c * KVSZ];
    kvt[idx] = s;
}

// ---------------------------------------------------------------------------
// Phase 2 (v5): register-tiled GEMM, Out[4096][65] = Qf[4096][64]*KV[64][65].
//  Per wave 64 rows x 32 cols, lane owns 8x4 tile; per k-chunk(4): 13
//  ds_read_b128 feed 160 FMAs; KV reused 8x, Q 4x in registers. Denominator
//  = KV row 64, accumulated per-lane for its own rows. Direct global stores.
//  (Round-6 measured ~20us ~= its 21us HBM floor -> unchanged.)
// ---------------------------------------------------------------------------
__global__ __launch_bounds__(256, 2)
void la_phase2(const float* __restrict__ Qin, const float* __restrict__ kvt,
               float* __restrict__ Out)
{
    __shared__ float sQ[128 * 68];   // 34.8 KB, row-major, stride 68
    __shared__ float sKV[KVSZ];      // 17.3 KB, [65][68] d-major

    const int b   = blockIdx.x;
    const int nh  = b >> 5;          // 32 l-chunks of 128 rows per (n,h)
    const int lc  = b & 31;
    const int n   = nh >> 3;
    const int h   = nh & 7;
    const int tid = threadIdx.x;
    const int w    = tid >> 6;
    const int lane = tid & 63;

    const float* Qc = Qin + (((size_t)n * L_L + (size_t)lc * 128) * H_H + h) * D_D;
    float*       Oc = Out + (((size_t)n * L_L + (size_t)lc * 128) * H_H + h) * D_D;

    // ---- stage KV_aug[65][68] into LDS (1105 float4, coalesced) ----
    {
        const float4* src = (const float4*)(kvt + (size_t)nh * KVSZ);
        float4*       dst = (float4*)sKV;
        #pragma unroll
        for (int it = 0; it < 4; ++it)
            dst[it * 256 + tid] = src[it * 256 + tid];
        if (tid < 81) dst[1024 + tid] = src[1024 + tid];
    }

    // ---- stage Q tile 128 rows x 64 cols (elu applied), stride 68 ----
    #pragma unroll
    for (int it = 0; it < 8; ++it) {
        const int slot = it * 256 + tid;   // 0..2047
        const int r    = slot >> 4;        // 0..127
        const int c4   = slot & 15;
        float4 v = *(const float4*)(Qc + (size_t)r * (H_H * D_D) + c4 * 4);
        v.x = elu1(v.x); v.y = elu1(v.y); v.z = elu1(v.z); v.w = elu1(v.w);
        *(float4*)&sQ[r * 68 + c4 * 4] = v;
    }
    __syncthreads();

    // ---- wave work assignment ----
    const int rt   = (w >> 1) * 64;        // row tile: 0 or 64
    const int wc   = w & 1;                // col half: 0 or 1
    const int rl   = lane & 7;             // row lane: rows rt + rl + 8j
    const int cg   = lane >> 3;            // col group
    const int ccol = wc * 32 + cg * 4;     // this lane's 4 output cols

    float acc[8][4];
    float den[8];
    #pragma unroll
    for (int j = 0; j < 8; ++j) {
        den[j] = 0.f;
        #pragma unroll
        for (int m = 0; m < 4; ++m) acc[j][m] = 0.f;
    }

    const int qbase = rt + rl;             // + 8j, stride-68 rows

    for (int kc = 0; kc < 16; ++kc) {
        // Q fragments: 8 rows x 4 k  (conflict-free b128: banks partition)
        float4 qv[8];
        #pragma unroll
        for (int j = 0; j < 8; ++j)
            qv[j] = *(const float4*)&sQ[(qbase + 8 * j) * 68 + kc * 4];
        // KV fragments: 4 k-rows x lane's 4 cols (conflict-free)
        const float4 kv0 = *(const float4*)&sKV[(kc * 4 + 0) * KVLD + ccol];
        const float4 kv1 = *(const float4*)&sKV[(kc * 4 + 1) * KVLD + ccol];
        const float4 kv2 = *(const float4*)&sKV[(kc * 4 + 2) * KVLD + ccol];
        const float4 kv3 = *(const float4*)&sKV[(kc * 4 + 3) * KVLD + ccol];
        // K_sum fragment: wave-uniform broadcast
        const float4 ks  = *(const float4*)&sKV[64 * KVLD + kc * 4];

        #pragma unroll
        for (int j = 0; j < 8; ++j) {
            const float q0 = qv[j].x, q1 = qv[j].y, q2 = qv[j].z, q3 = qv[j].w;
            den[j] = fmaf(q0, ks.x, den[j]);
            den[j] = fmaf(q1, ks.y, den[j]);
            den[j] = fmaf(q2, ks.z, den[j]);
            den[j] = fmaf(q3, ks.w, den[j]);
            acc[j][0] = fmaf(q0, kv0.x, acc[j][0]);
            acc[j][0] = fmaf(q1, kv1.x, acc[j][0]);
            acc[j][0] = fmaf(q2, kv2.x, acc[j][0]);
            acc[j][0] = fmaf(q3, kv3.x, acc[j][0]);
            acc[j][1] = fmaf(q0, kv0.y, acc[j][1]);
            acc[j][1] = fmaf(q1, kv1.y, acc[j][1]);
            acc[j][1] = fmaf(q2, kv2.y, acc[j][1]);
            acc[j][1] = fmaf(q3, kv3.y, acc[j][1]);
            acc[j][2] = fmaf(q0, kv0.z, acc[j][2]);
            acc[j][2] = fmaf(q1, kv1.z, acc[j][2]);
            acc[j][2] = fmaf(q2, kv2.z, acc[j][2]);
            acc[j][2] = fmaf(q3, kv3.z, acc[j][2]);
            acc[j][3] = fmaf(q0, kv0.w, acc[j][3]);
            acc[j][3] = fmaf(q1, kv1.w, acc[j][3]);
            acc[j][3] = fmaf(q2, kv2.w, acc[j][3]);
            acc[j][3] = fmaf(q3, kv3.w, acc[j][3]);
        }
    }

    // ---- epilogue: scale by 1/(den+eps), direct coalesced global stores ----
    #pragma unroll
    for (int j = 0; j < 8; ++j) {
        const float rz = 1.0f / (den[j] + 1e-6f);
        *(float4*)(Oc + (size_t)(qbase + 8 * j) * (H_H * D_D) + ccol) =
            make_float4(acc[j][0] * rz, acc[j][1] * rz,
                        acc[j][2] * rz, acc[j][3] * rz);
    }
}

// ---------------------------------------------------------------------------
extern "C" void kernel_launch(void* const* d_in, const int* in_sizes, int n_in,
                              void* d_out, int out_size, void* d_ws, size_t ws_size,
                              hipStream_t stream)
{
    const float* Q = (const float*)d_in[0];
    const float* K = (const float*)d_in[1];
    const float* V = (const float*)d_in[2];
    float* out = (float*)d_out;

    // ws layout: [ kvt: NH*KVSZ floats ][ partials: NH*split*KVSZ floats ]
    float* kvt = (float*)d_ws;
    const size_t kvt_bytes = (size_t)NH * KVSZ * sizeof(float);

    int split = 16;
    while (split > 1 &&
           kvt_bytes + (size_t)NH * split * KVSZ * sizeof(float) > ws_size)
        split >>= 1;
    float* partials = kvt + (size_t)NH * KVSZ;
    const int schunk = S_S / split;

    la_phase1<<<NH * split, 256, 0, stream>>>(K, V, partials, split, schunk);

    const int red_blocks = (NH * KVSZ + 255) / 256;   // 1105 exactly
    la_reduce<<<red_blocks, 256, 0, stream>>>(partials, kvt, split);

    la_phase2<<<NH * (L_L / 128), 256, 0, stream>>>(Q, kvt, out);
}

// Round 8
// 386.617 us; speedup vs baseline: 1.3780x; 1.3780x over previous
//
#include <hip/hip_runtime.h>
#include <hip/hip_bf16.h>
#include <cstddef>
#include <cstdint>

// Problem constants (fixed by the reference setup)
#define N_B   8
#define L_L   4096
#define S_S   4096
#define H_H   8
#define D_D   64
#define NH    64          // N_B * H_H
// KV_aug layout (d-major): rows 0..63 = KV[d][v] (stride 68, cols 64..67 pad),
// row 64 = K_sum[d] (indexed by d in cols 0..63). KVSZ floats per (n,h).
#define KVLD  68
#define KVSZ  (65 * KVLD)   // 4420

__device__ __forceinline__ float elu1(float x) {
    // elu(x)+1 : x>0 ? x+1 : exp(x)
    return x > 0.f ? x + 1.f : __expf(x);
}

// ---------------------------------------------------------------------------
// Phase 1 (v3): double-buffered LDS + async reg-staging, ONE barrier/tile.
//  v2 (round 7) REGRESSED 72->496us: __launch_bounds__(256,4) caps regs at
//  128; gfx950's unified VGPR/AGPR file charges acc[8][8] (64 AGPR) to the
//  same budget, and the +16 staged VGPRs overflowed it -> staged tile spilled
//  to scratch (FETCH 69->643MB, WRITE 1.28GB, VALU 4%).
//  v3: identical schedule, __launch_bounds__(256,3) -> cap ~168 regs
//  (need ~145). 3 blocks/CU (12 waves/CU) — same occupancy v1 measured.
// ---------------------------------------------------------------------------
__global__ __launch_bounds__(256, 3)
void la_phase1(const float* __restrict__ Kin, const float* __restrict__ Vin,
               float* __restrict__ partials, int split, int schunk)
{
    __shared__ union {
        struct { float K[2][32 * 64]; float V[2][32 * 64]; } st; // 32 KB
        float acc[64 * 68];                                      // 17.3 KB
    } sm;
    __shared__ float sKsumP[4 * 64];     // per-wave ksum partials

    const int b     = blockIdx.x;
    const int nh    = b / split;
    const int chunk = b - nh * split;
    const int n     = nh >> 3;
    const int h     = nh & 7;
    const int s0    = chunk * schunk;

    const int tid  = threadIdx.x;
    const int w    = tid >> 6;
    const int lane = tid & 63;
    const int dg   = lane >> 3;   // d-group: d = dg*8 + i
    const int vg   = lane & 7;    // v-group: v = vg*8 + j

    float acc[8][8];
    #pragma unroll
    for (int i = 0; i < 8; ++i)
        #pragma unroll
        for (int j = 0; j < 8; ++j) acc[i][j] = 0.f;
    float ksum = 0.f;

    // staging map: 256 threads cover 32 rows x 64 cols, 8 floats each
    const int sr = tid >> 3;          // 0..31
    const int sc = (tid & 7) * 8;     // 0,8,...,56
    const int kd = lane;              // ksum d index (per-wave full coverage)

    const float* Kb = Kin + (size_t)n * S_S * (H_H * D_D) + h * D_D;
    const float* Vb = Vin + (size_t)n * S_S * (H_H * D_D) + h * D_D;

    const int ntiles = schunk >> 5;   // tiles of 32 s-rows

    // ---- prologue: stage tile 0 into buf 0 ----
    {
        const float* kg = Kb + (size_t)(s0 + sr) * (H_H * D_D) + sc;
        const float* vp = Vb + (size_t)(s0 + sr) * (H_H * D_D) + sc;
        float4 ka = *(const float4*)kg;
        float4 kc = *(const float4*)(kg + 4);
        float4 va = *(const float4*)vp;
        float4 vc = *(const float4*)(vp + 4);
        ka.x = elu1(ka.x); ka.y = elu1(ka.y); ka.z = elu1(ka.z); ka.w = elu1(ka.w);
        kc.x = elu1(kc.x); kc.y = elu1(kc.y); kc.z = elu1(kc.z); kc.w = elu1(kc.w);
        *(float4*)&sm.st.K[0][sr * 64 + sc]     = ka;
        *(float4*)&sm.st.K[0][sr * 64 + sc + 4] = kc;
        *(float4*)&sm.st.V[0][sr * 64 + sc]     = va;
        *(float4*)&sm.st.V[0][sr * 64 + sc + 4] = vc;
    }

    for (int t = 0; t < ntiles; ++t) {
        const int buf = t & 1;
        __syncthreads();               // buf's staged writes visible

        // issue next tile's loads (in flight across the compute below)
        float4 ka, kc, va, vc;
        const bool more = (t + 1 < ntiles);
        if (more) {
            const int srow = s0 + (t + 1) * 32;
            const float* kg = Kb + (size_t)(srow + sr) * (H_H * D_D) + sc;
            const float* vp = Vb + (size_t)(srow + sr) * (H_H * D_D) + sc;
            ka = *(const float4*)kg;
            kc = *(const float4*)(kg + 4);
            va = *(const float4*)vp;
            vc = *(const float4*)(vp + 4);
        }

        const float* sKb = sm.st.K[buf];
        const float* sVb = sm.st.V[buf];

        // wave w handles s-local rows w*8 .. w*8+7
        #pragma unroll
        for (int sl = 0; sl < 8; ++sl) {
            const int s = w * 8 + sl;
            const float4 k0 = *(const float4*)&sKb[s * 64 + dg * 8];
            const float4 k1 = *(const float4*)&sKb[s * 64 + dg * 8 + 4];
            const float4 v0 = *(const float4*)&sVb[s * 64 + vg * 8];
            const float4 v1 = *(const float4*)&sVb[s * 64 + vg * 8 + 4];
            const float kf[8] = {k0.x, k0.y, k0.z, k0.w, k1.x, k1.y, k1.z, k1.w};
            const float vf[8] = {v0.x, v0.y, v0.z, v0.w, v1.x, v1.y, v1.z, v1.w};
            #pragma unroll
            for (int i = 0; i < 8; ++i)
                #pragma unroll
                for (int j = 0; j < 8; ++j)
                    acc[i][j] = fmaf(kf[i], vf[j], acc[i][j]);
        }
        // K_sum partial over the same 8 rows this wave consumed
        #pragma unroll
        for (int sl = 0; sl < 8; ++sl)
            ksum += sKb[(w * 8 + sl) * 64 + kd];

        // store staged tile t+1 into the OTHER buffer (no hazard with slow
        // waves still computing tile t from buf)
        if (more) {
            ka.x = elu1(ka.x); ka.y = elu1(ka.y); ka.z = elu1(ka.z); ka.w = elu1(ka.w);
            kc.x = elu1(kc.x); kc.y = elu1(kc.y); kc.z = elu1(kc.z); kc.w = elu1(kc.w);
            float* dK = sm.st.K[buf ^ 1];
            float* dV = sm.st.V[buf ^ 1];
            *(float4*)&dK[sr * 64 + sc]     = ka;
            *(float4*)&dK[sr * 64 + sc + 4] = kc;
            *(float4*)&dV[sr * 64 + sc]     = va;
            *(float4*)&dV[sr * 64 + sc + 4] = vc;
        }
    }
    __syncthreads();   // all compute reads done; staging buffers now reusable

    // cross-wave reduce of acc into sm.acc[d][v] (stride 68), sequential & exact
    for (int ww = 0; ww < 4; ++ww) {
        if (w == ww) {
            #pragma unroll
            for (int i = 0; i < 8; ++i) {
                float* p = &sm.acc[(dg * 8 + i) * 68 + vg * 8];
                if (ww == 0) {
                    *(float4*)p       = make_float4(acc[i][0], acc[i][1], acc[i][2], acc[i][3]);
                    *(float4*)(p + 4) = make_float4(acc[i][4], acc[i][5], acc[i][6], acc[i][7]);
                } else {
                    float4 a0 = *(const float4*)p;
                    float4 a1 = *(const float4*)(p + 4);
                    a0.x += acc[i][0]; a0.y += acc[i][1]; a0.z += acc[i][2]; a0.w += acc[i][3];
                    a1.x += acc[i][4]; a1.y += acc[i][5]; a1.z += acc[i][6]; a1.w += acc[i][7];
                    *(float4*)p       = a0;
                    *(float4*)(p + 4) = a1;
                }
            }
        }
        __syncthreads();
    }

    // ksum: deterministic 4-way reduce (one slot per (wave, d))
    sKsumP[w * 64 + kd] = ksum;
    __syncthreads();

    // write this block's partial KV_aug[65][68] d-major (row 64 = K_sum, pads 0)
    float* outp = partials + (size_t)b * KVSZ;
    for (int idx = tid; idx < KVSZ; idx += 256) {
        const int r = idx / KVLD;
        const int c = idx - r * KVLD;
        float val = 0.f;
        if (c < 64) {
            if (r < 64)
                val = sm.acc[idx];   // sm.acc is [d][v] stride 68 == same layout
            else
                val = sKsumP[c] + sKsumP[64 + c] + sKsumP[128 + c] + sKsumP[192 + c];
        }
        outp[idx] = val;
    }
}

// ---------------------------------------------------------------------------
// Reduce: sum the `split` partials per (n,h) -> kvt[nh][65][68]
// ---------------------------------------------------------------------------
__global__ __launch_bounds__(256)
void la_reduce(const float* __restrict__ partials, float* __restrict__ kvt, int split)
{
    const int idx = blockIdx.x * 256 + threadIdx.x;
    if (idx >= NH * KVSZ) return;
    const int nh  = idx / KVSZ;
    const int rem = idx - nh * KVSZ;
    const float* p = partials + (size_t)nh * split * KVSZ + rem;
    float s = 0.f;
    for (int c = 0; c < split; ++c) s += p[(size_t)c * KVSZ];
    kvt[idx] = s;
}

// ---------------------------------------------------------------------------
// Phase 2 (v5): register-tiled GEMM, Out[4096][65] = Qf[4096][64]*KV[64][65].
//  Per wave 64 rows x 32 cols, lane owns 8x4 tile; per k-chunk(4): 13
//  ds_read_b128 feed 160 FMAs; KV reused 8x, Q 4x in registers. Denominator
//  = KV row 64, accumulated per-lane for its own rows. Direct global stores.
//  (Round-6 measured ~20us ~= its 21us HBM floor -> unchanged.)
// ---------------------------------------------------------------------------
__global__ __launch_bounds__(256, 2)
void la_phase2(const float* __restrict__ Qin, const float* __restrict__ kvt,
               float* __restrict__ Out)
{
    __shared__ float sQ[128 * 68];   // 34.8 KB, row-major, stride 68
    __shared__ float sKV[KVSZ];      // 17.3 KB, [65][68] d-major

    const int b   = blockIdx.x;
    const int nh  = b >> 5;          // 32 l-chunks of 128 rows per (n,h)
    const int lc  = b & 31;
    const int n   = nh >> 3;
    const int h   = nh & 7;
    const int tid = threadIdx.x;
    const int w    = tid >> 6;
    const int lane = tid & 63;

    const float* Qc = Qin + (((size_t)n * L_L + (size_t)lc * 128) * H_H + h) * D_D;
    float*       Oc = Out + (((size_t)n * L_L + (size_t)lc * 128) * H_H + h) * D_D;

    // ---- stage KV_aug[65][68] into LDS (1105 float4, coalesced) ----
    {
        const float4* src = (const float4*)(kvt + (size_t)nh * KVSZ);
        float4*       dst = (float4*)sKV;
        #pragma unroll
        for (int it = 0; it < 4; ++it)
            dst[it * 256 + tid] = src[it * 256 + tid];
        if (tid < 81) dst[1024 + tid] = src[1024 + tid];
    }

    // ---- stage Q tile 128 rows x 64 cols (elu applied), stride 68 ----
    #pragma unroll
    for (int it = 0; it < 8; ++it) {
        const int slot = it * 256 + tid;   // 0..2047
        const int r    = slot >> 4;        // 0..127
        const int c4   = slot & 15;
        float4 v = *(const float4*)(Qc + (size_t)r * (H_H * D_D) + c4 * 4);
        v.x = elu1(v.x); v.y = elu1(v.y); v.z = elu1(v.z); v.w = elu1(v.w);
        *(float4*)&sQ[r * 68 + c4 * 4] = v;
    }
    __syncthreads();

    // ---- wave work assignment ----
    const int rt   = (w >> 1) * 64;        // row tile: 0 or 64
    const int wc   = w & 1;                // col half: 0 or 1
    const int rl   = lane & 7;             // row lane: rows rt + rl + 8j
    const int cg   = lane >> 3;            // col group
    const int ccol = wc * 32 + cg * 4;     // this lane's 4 output cols

    float acc[8][4];
    float den[8];
    #pragma unroll
    for (int j = 0; j < 8; ++j) {
        den[j] = 0.f;
        #pragma unroll
        for (int m = 0; m < 4; ++m) acc[j][m] = 0.f;
    }

    const int qbase = rt + rl;             // + 8j, stride-68 rows

    for (int kc = 0; kc < 16; ++kc) {
        // Q fragments: 8 rows x 4 k  (conflict-free b128: banks partition)
        float4 qv[8];
        #pragma unroll
        for (int j = 0; j < 8; ++j)
            qv[j] = *(const float4*)&sQ[(qbase + 8 * j) * 68 + kc * 4];
        // KV fragments: 4 k-rows x lane's 4 cols (conflict-free)
        const float4 kv0 = *(const float4*)&sKV[(kc * 4 + 0) * KVLD + ccol];
        const float4 kv1 = *(const float4*)&sKV[(kc * 4 + 1) * KVLD + ccol];
        const float4 kv2 = *(const float4*)&sKV[(kc * 4 + 2) * KVLD + ccol];
        const float4 kv3 = *(const float4*)&sKV[(kc * 4 + 3) * KVLD + ccol];
        // K_sum fragment: wave-uniform broadcast
        const float4 ks  = *(const float4*)&sKV[64 * KVLD + kc * 4];

        #pragma unroll
        for (int j = 0; j < 8; ++j) {
            const float q0 = qv[j].x, q1 = qv[j].y, q2 = qv[j].z, q3 = qv[j].w;
            den[j] = fmaf(q0, ks.x, den[j]);
            den[j] = fmaf(q1, ks.y, den[j]);
            den[j] = fmaf(q2, ks.z, den[j]);
            den[j] = fmaf(q3, ks.w, den[j]);
            acc[j][0] = fmaf(q0, kv0.x, acc[j][0]);
            acc[j][0] = fmaf(q1, kv1.x, acc[j][0]);
            acc[j][0] = fmaf(q2, kv2.x, acc[j][0]);
            acc[j][0] = fmaf(q3, kv3.x, acc[j][0]);
            acc[j][1] = fmaf(q0, kv0.y, acc[j][1]);
            acc[j][1] = fmaf(q1, kv1.y, acc[j][1]);
            acc[j][1] = fmaf(q2, kv2.y, acc[j][1]);
            acc[j][1] = fmaf(q3, kv3.y, acc[j][1]);
            acc[j][2] = fmaf(q0, kv0.z, acc[j][2]);
            acc[j][2] = fmaf(q1, kv1.z, acc[j][2]);
            acc[j][2] = fmaf(q2, kv2.z, acc[j][2]);
            acc[j][2] = fmaf(q3, kv3.z, acc[j][2]);
            acc[j][3] = fmaf(q0, kv0.w, acc[j][3]);
            acc[j][3] = fmaf(q1, kv1.w, acc[j][3]);
            acc[j][3] = fmaf(q2, kv2.w, acc[j][3]);
            acc[j][3] = fmaf(q3, kv3.w, acc[j][3]);
        }
    }

    // ---- epilogue: scale by 1/(den+eps), direct coalesced global stores ----
    #pragma unroll
    for (int j = 0; j < 8; ++j) {
        const float rz = 1.0f / (den[j] + 1e-6f);
        *(float4*)(Oc + (size_t)(qbase + 8 * j) * (H_H * D_D) + ccol) =
            make_float4(acc[j][0] * rz, acc[j][1] * rz,
                        acc[j][2] * rz, acc[j][3] * rz);
    }
}

// ---------------------------------------------------------------------------
extern "C" void kernel_launch(void* const* d_in, const int* in_sizes, int n_in,
                              void* d_out, int out_size, void* d_ws, size_t ws_size,
                              hipStream_t stream)
{
    const float* Q = (const float*)d_in[0];
    const float* K = (const float*)d_in[1];
    const float* V = (const float*)d_in[2];
    float* out = (float*)d_out;

    // ws layout: [ kvt: NH*KVSZ floats ][ partials: NH*split*KVSZ floats ]
    float* kvt = (float*)d_ws;
    const size_t kvt_bytes = (size_t)NH * KVSZ * sizeof(float);

    int split = 16;
    while (split > 1 &&
           kvt_bytes + (size_t)NH * split * KVSZ * sizeof(float) > ws_size)
        split >>= 1;
    float* partials = kvt + (size_t)NH * KVSZ;
    const int schunk = S_S / split;

    la_phase1<<<NH * split, 256, 0, stream>>>(K, V, partials, split, schunk);

    const int red_blocks = (NH * KVSZ + 255) / 256;   // 1105 exactly
    la_reduce<<<red_blocks, 256, 0, stream>>>(partials, kvt, split);

    la_phase2<<<NH * (L_L / 128), 256, 0, stream>>>(Q, kvt, out);
}

// Round 9
// 385.557 us; speedup vs baseline: 1.3817x; 1.0028x over previous
//
#include <hip/hip_runtime.h>
#include <hip/hip_bf16.h>
#include <cstddef>
#include <cstdint>

// Problem constants (fixed by the reference setup)
#define N_B   8
#define L_L   4096
#define S_S   4096
#define H_H   8
#define D_D   64
#define NH    64          // N_B * H_H
// KV_aug layout (d-major): rows 0..63 = KV[d][v] (stride 68, cols 64..67 pad),
// row 64 = K_sum[d] (indexed by d in cols 0..63). KVSZ floats per (n,h).
#define KVLD  68
#define KVSZ  (65 * KVLD)   // 4420

typedef const float __attribute__((address_space(1)))* gas_fp;
typedef float __attribute__((address_space(3)))* las_fp;

__device__ __forceinline__ float elu1(float x) {
    // elu(x)+1 : x>0 ? x+1 : exp(x)
    return x > 0.f ? x + 1.f : __expf(x);
}

// ---------------------------------------------------------------------------
// Phase 1 (v4): double-buffered, ONE barrier/tile.
//  v2/v3 post-mortem: holding 16 staged VGPRs (K+V) across the unrolled
//  512-FMA body + 64-reg acc made the allocator spill part of acc to scratch
//  (v2: FETCH 643MB @cap128; v3: 320MB @cap170 — allocator chose to spill).
//  v4: V staged via __builtin_amdgcn_global_load_lds (async DMA, ZERO held
//  regs, no elu needed on V; __syncthreads' vmcnt(0) drain at the next
//  barrier = free T14). K (needs fused elu) reg-staged: only 8 held VGPRs.
//  Schedule per tile: barrier -> issue V-DMA(t+1)->bufV^1 + load K(t+1)->regs
//  -> compute(t) -> elu+ds_write K(t+1)->bufK^1.
// ---------------------------------------------------------------------------
__global__ __launch_bounds__(256, 3)
void la_phase1(const float* __restrict__ Kin, const float* __restrict__ Vin,
               float* __restrict__ partials, int split, int schunk)
{
    __shared__ union {
        struct { float K[2][32 * 64]; float V[2][32 * 64]; } st; // 32 KB
        float acc[64 * 68];                                      // 17.3 KB
    } sm;
    __shared__ float sKsumP[4 * 64];     // per-wave ksum partials

    const int b     = blockIdx.x;
    const int nh    = b / split;
    const int chunk = b - nh * split;
    const int n     = nh >> 3;
    const int h     = nh & 7;
    const int s0    = chunk * schunk;

    const int tid  = threadIdx.x;
    const int w    = tid >> 6;
    const int lane = tid & 63;
    const int dg   = lane >> 3;   // d-group: d = dg*8 + i
    const int vg   = lane & 7;    // v-group: v = vg*8 + j

    float acc[8][8];
    #pragma unroll
    for (int i = 0; i < 8; ++i)
        #pragma unroll
        for (int j = 0; j < 8; ++j) acc[i][j] = 0.f;
    float ksum = 0.f;

    // K staging map: 256 threads cover 32 rows x 64 cols, 8 floats each
    const int sr = tid >> 3;          // 0..31
    const int sc = (tid & 7) * 8;     // 0,8,...,56
    const int kd = lane;              // ksum d index (per-wave full coverage)

    const float* Kb = Kin + (size_t)n * S_S * (H_H * D_D) + h * D_D;
    const float* Vb = Vin + (size_t)n * S_S * (H_H * D_D) + h * D_D;

    // V DMA map: wave w issues 2 chunks of 1024B; lane covers 16B at
    // lds_off = chunk*1024 + lane*16  (linear == row-major [32][64] tile)
    const int vrow0 = (w * 2 + 0) * 4 + (lane >> 4);   // + srow
    const int vrow1 = (w * 2 + 1) * 4 + (lane >> 4);
    const int vcol  = (lane & 15) * 4;

    const int ntiles = schunk >> 5;   // tiles of 32 s-rows

    // ---- prologue: stage tile 0 into buf 0 ----
    {
        __builtin_amdgcn_global_load_lds(
            (gas_fp)(Vb + (size_t)(s0 + vrow0) * (H_H * D_D) + vcol),
            (las_fp)&sm.st.V[0][(w * 2 + 0) * 256], 16, 0, 0);
        __builtin_amdgcn_global_load_lds(
            (gas_fp)(Vb + (size_t)(s0 + vrow1) * (H_H * D_D) + vcol),
            (las_fp)&sm.st.V[0][(w * 2 + 1) * 256], 16, 0, 0);
        const float* kg = Kb + (size_t)(s0 + sr) * (H_H * D_D) + sc;
        float4 ka = *(const float4*)kg;
        float4 kc = *(const float4*)(kg + 4);
        ka.x = elu1(ka.x); ka.y = elu1(ka.y); ka.z = elu1(ka.z); ka.w = elu1(ka.w);
        kc.x = elu1(kc.x); kc.y = elu1(kc.y); kc.z = elu1(kc.z); kc.w = elu1(kc.w);
        *(float4*)&sm.st.K[0][sr * 64 + sc]     = ka;
        *(float4*)&sm.st.K[0][sr * 64 + sc + 4] = kc;
    }

    for (int t = 0; t < ntiles; ++t) {
        const int buf = t & 1;
        __syncthreads();   // drains V-DMA (vmcnt0) + K ds_writes for buf

        const bool more = (t + 1 < ntiles);
        float4 ka, kc;
        if (more) {
            const int srow = s0 + (t + 1) * 32;
            // async V DMA into the other buffer (zero registers held)
            __builtin_amdgcn_global_load_lds(
                (gas_fp)(Vb + (size_t)(srow + vrow0) * (H_H * D_D) + vcol),
                (las_fp)&sm.st.V[buf ^ 1][(w * 2 + 0) * 256], 16, 0, 0);
            __builtin_amdgcn_global_load_lds(
                (gas_fp)(Vb + (size_t)(srow + vrow1) * (H_H * D_D) + vcol),
                (las_fp)&sm.st.V[buf ^ 1][(w * 2 + 1) * 256], 16, 0, 0);
            // K loads in flight across the compute (8 held VGPRs)
            const float* kg = Kb + (size_t)(srow + sr) * (H_H * D_D) + sc;
            ka = *(const float4*)kg;
            kc = *(const float4*)(kg + 4);
        }

        const float* sKb = sm.st.K[buf];
        const float* sVb = sm.st.V[buf];

        // wave w handles s-local rows w*8 .. w*8+7
        #pragma unroll
        for (int sl = 0; sl < 8; ++sl) {
            const int s = w * 8 + sl;
            const float4 k0 = *(const float4*)&sKb[s * 64 + dg * 8];
            const float4 k1 = *(const float4*)&sKb[s * 64 + dg * 8 + 4];
            const float4 v0 = *(const float4*)&sVb[s * 64 + vg * 8];
            const float4 v1 = *(const float4*)&sVb[s * 64 + vg * 8 + 4];
            const float kf[8] = {k0.x, k0.y, k0.z, k0.w, k1.x, k1.y, k1.z, k1.w};
            const float vf[8] = {v0.x, v0.y, v0.z, v0.w, v1.x, v1.y, v1.z, v1.w};
            #pragma unroll
            for (int i = 0; i < 8; ++i)
                #pragma unroll
                for (int j = 0; j < 8; ++j)
                    acc[i][j] = fmaf(kf[i], vf[j], acc[i][j]);
        }
        // K_sum partial over the same 8 rows this wave consumed
        #pragma unroll
        for (int sl = 0; sl < 8; ++sl)
            ksum += sKb[(w * 8 + sl) * 64 + kd];

        // elu + store staged K(t+1) into the OTHER buffer
        if (more) {
            ka.x = elu1(ka.x); ka.y = elu1(ka.y); ka.z = elu1(ka.z); ka.w = elu1(ka.w);
            kc.x = elu1(kc.x); kc.y = elu1(kc.y); kc.z = elu1(kc.z); kc.w = elu1(kc.w);
            float* dK = sm.st.K[buf ^ 1];
            *(float4*)&dK[sr * 64 + sc]     = ka;
            *(float4*)&dK[sr * 64 + sc + 4] = kc;
        }
    }
    __syncthreads();   // all compute reads done; staging buffers now reusable

    // cross-wave reduce of acc into sm.acc[d][v] (stride 68), sequential & exact
    for (int ww = 0; ww < 4; ++ww) {
        if (w == ww) {
            #pragma unroll
            for (int i = 0; i < 8; ++i) {
                float* p = &sm.acc[(dg * 8 + i) * 68 + vg * 8];
                if (ww == 0) {
                    *(float4*)p       = make_float4(acc[i][0], acc[i][1], acc[i][2], acc[i][3]);
                    *(float4*)(p + 4) = make_float4(acc[i][4], acc[i][5], acc[i][6], acc[i][7]);
                } else {
                    float4 a0 = *(const float4*)p;
                    float4 a1 = *(const float4*)(p + 4);
                    a0.x += acc[i][0]; a0.y += acc[i][1]; a0.z += acc[i][2]; a0.w += acc[i][3];
                    a1.x += acc[i][4]; a1.y += acc[i][5]; a1.z += acc[i][6]; a1.w += acc[i][7];
                    *(float4*)p       = a0;
                    *(float4*)(p + 4) = a1;
                }
            }
        }
        __syncthreads();
    }

    // ksum: deterministic 4-way reduce (one slot per (wave, d))
    sKsumP[w * 64 + kd] = ksum;
    __syncthreads();

    // write this block's partial KV_aug[65][68] d-major (row 64 = K_sum, pads 0)
    float* outp = partials + (size_t)b * KVSZ;
    for (int idx = tid; idx < KVSZ; idx += 256) {
        const int r = idx / KVLD;
        const int c = idx - r * KVLD;
        float val = 0.f;
        if (c < 64) {
            if (r < 64)
                val = sm.acc[idx];   // sm.acc is [d][v] stride 68 == same layout
            else
                val = sKsumP[c] + sKsumP[64 + c] + sKsumP[128 + c] + sKsumP[192 + c];
        }
        outp[idx] = val;
    }
}

// ---------------------------------------------------------------------------
// Reduce: sum the `split` partials per (n,h) -> kvt[nh][65][68]
// ---------------------------------------------------------------------------
__global__ __launch_bounds__(256)
void la_reduce(const float* __restrict__ partials, float* __restrict__ kvt, int split)
{
    const int idx = blockIdx.x * 256 + threadIdx.x;
    if (idx >= NH * KVSZ) return;
    const int nh  = idx / KVSZ;
    const int rem = idx - nh * KVSZ;
    const float* p = partials + (size_t)nh * split * KVSZ + rem;
    float s = 0.f;
    for (int c = 0; c < split; ++c) s += p[(size_t)c * KVSZ];
    kvt[idx] = s;
}

// ---------------------------------------------------------------------------
// Phase 2 (v5): register-tiled GEMM, Out[4096][65] = Qf[4096][64]*KV[64][65].
//  Per wave 64 rows x 32 cols, lane owns 8x4 tile; per k-chunk(4): 13
//  ds_read_b128 feed 160 FMAs; KV reused 8x, Q 4x in registers. Denominator
//  = KV row 64, accumulated per-lane for its own rows. Direct global stores.
//  (Round-6 measured ~20us ~= its 21us HBM floor -> unchanged.)
// ---------------------------------------------------------------------------
__global__ __launch_bounds__(256, 2)
void la_phase2(const float* __restrict__ Qin, const float* __restrict__ kvt,
               float* __restrict__ Out)
{
    __shared__ float sQ[128 * 68];   // 34.8 KB, row-major, stride 68
    __shared__ float sKV[KVSZ];      // 17.3 KB, [65][68] d-major

    const int b   = blockIdx.x;
    const int nh  = b >> 5;          // 32 l-chunks of 128 rows per (n,h)
    const int lc  = b & 31;
    const int n   = nh >> 3;
    const int h   = nh & 7;
    const int tid = threadIdx.x;
    const int w    = tid >> 6;
    const int lane = tid & 63;

    const float* Qc = Qin + (((size_t)n * L_L + (size_t)lc * 128) * H_H + h) * D_D;
    float*       Oc = Out + (((size_t)n * L_L + (size_t)lc * 128) * H_H + h) * D_D;

    // ---- stage KV_aug[65][68] into LDS (1105 float4, coalesced) ----
    {
        const float4* src = (const float4*)(kvt + (size_t)nh * KVSZ);
        float4*       dst = (float4*)sKV;
        #pragma unroll
        for (int it = 0; it < 4; ++it)
            dst[it * 256 + tid] = src[it * 256 + tid];
        if (tid < 81) dst[1024 + tid] = src[1024 + tid];
    }

    // ---- stage Q tile 128 rows x 64 cols (elu applied), stride 68 ----
    #pragma unroll
    for (int it = 0; it < 8; ++it) {
        const int slot = it * 256 + tid;   // 0..2047
        const int r    = slot >> 4;        // 0..127
        const int c4   = slot & 15;
        float4 v = *(const float4*)(Qc + (size_t)r * (H_H * D_D) + c4 * 4);
        v.x = elu1(v.x); v.y = elu1(v.y); v.z = elu1(v.z); v.w = elu1(v.w);
        *(float4*)&sQ[r * 68 + c4 * 4] = v;
    }
    __syncthreads();

    // ---- wave work assignment ----
    const int rt   = (w >> 1) * 64;        // row tile: 0 or 64
    const int wc   = w & 1;                // col half: 0 or 1
    const int rl   = lane & 7;             // row lane: rows rt + rl + 8j
    const int cg   = lane >> 3;            // col group
    const int ccol = wc * 32 + cg * 4;     // this lane's 4 output cols

    float acc[8][4];
    float den[8];
    #pragma unroll
    for (int j = 0; j < 8; ++j) {
        den[j] = 0.f;
        #pragma unroll
        for (int m = 0; m < 4; ++m) acc[j][m] = 0.f;
    }

    const int qbase = rt + rl;             // + 8j, stride-68 rows

    for (int kc = 0; kc < 16; ++kc) {
        // Q fragments: 8 rows x 4 k  (conflict-free b128: banks partition)
        float4 qv[8];
        #pragma unroll
        for (int j = 0; j < 8; ++j)
            qv[j] = *(const float4*)&sQ[(qbase + 8 * j) * 68 + kc * 4];
        // KV fragments: 4 k-rows x lane's 4 cols (conflict-free)
        const float4 kv0 = *(const float4*)&sKV[(kc * 4 + 0) * KVLD + ccol];
        const float4 kv1 = *(const float4*)&sKV[(kc * 4 + 1) * KVLD + ccol];
        const float4 kv2 = *(const float4*)&sKV[(kc * 4 + 2) * KVLD + ccol];
        const float4 kv3 = *(const float4*)&sKV[(kc * 4 + 3) * KVLD + ccol];
        // K_sum fragment: wave-uniform broadcast
        const float4 ks  = *(const float4*)&sKV[64 * KVLD + kc * 4];

        #pragma unroll
        for (int j = 0; j < 8; ++j) {
            const float q0 = qv[j].x, q1 = qv[j].y, q2 = qv[j].z, q3 = qv[j].w;
            den[j] = fmaf(q0, ks.x, den[j]);
            den[j] = fmaf(q1, ks.y, den[j]);
            den[j] = fmaf(q2, ks.z, den[j]);
            den[j] = fmaf(q3, ks.w, den[j]);
            acc[j][0] = fmaf(q0, kv0.x, acc[j][0]);
            acc[j][0] = fmaf(q1, kv1.x, acc[j][0]);
            acc[j][0] = fmaf(q2, kv2.x, acc[j][0]);
            acc[j][0] = fmaf(q3, kv3.x, acc[j][0]);
            acc[j][1] = fmaf(q0, kv0.y, acc[j][1]);
            acc[j][1] = fmaf(q1, kv1.y, acc[j][1]);
            acc[j][1] = fmaf(q2, kv2.y, acc[j][1]);
            acc[j][1] = fmaf(q3, kv3.y, acc[j][1]);
            acc[j][2] = fmaf(q0, kv0.z, acc[j][2]);
            acc[j][2] = fmaf(q1, kv1.z, acc[j][2]);
            acc[j][2] = fmaf(q2, kv2.z, acc[j][2]);
            acc[j][2] = fmaf(q3, kv3.z, acc[j][2]);
            acc[j][3] = fmaf(q0, kv0.w, acc[j][3]);
            acc[j][3] = fmaf(q1, kv1.w, acc[j][3]);
            acc[j][3] = fmaf(q2, kv2.w, acc[j][3]);
            acc[j][3] = fmaf(q3, kv3.w, acc[j][3]);
        }
    }

    // ---- epilogue: scale by 1/(den+eps), direct coalesced global stores ----
    #pragma unroll
    for (int j = 0; j < 8; ++j) {
        const float rz = 1.0f / (den[j] + 1e-6f);
        *(float4*)(Oc + (size_t)(qbase + 8 * j) * (H_H * D_D) + ccol) =
            make_float4(acc[j][0] * rz, acc[j][1] * rz,
                        acc[j][2] * rz, acc[j][3] * rz);
    }
}

// ---------------------------------------------------------------------------
extern "C" void kernel_launch(void* const* d_in, const int* in_sizes, int n_in,
                              void* d_out, int out_size, void* d_ws, size_t ws_size,
                              hipStream_t stream)
{
    const float* Q = (const float*)d_in[0];
    const float* K = (const float*)d_in[1];
    const float* V = (const float*)d_in[2];
    float* out = (float*)d_out;

    // ws layout: [ kvt: NH*KVSZ floats ][ partials: NH*split*KVSZ floats ]
    float* kvt = (float*)d_ws;
    const size_t kvt_bytes = (size_t)NH * KVSZ * sizeof(float);

    int split = 16;
    while (split > 1 &&
           kvt_bytes + (size_t)NH * split * KVSZ * sizeof(float) > ws_size)
        split >>= 1;
    float* partials = kvt + (size_t)NH * KVSZ;
    const int schunk = S_S / split;

    la_phase1<<<NH * split, 256, 0, stream>>>(K, V, partials, split, schunk);

    const int red_blocks = (NH * KVSZ + 255) / 256;   // 1105 exactly
    la_reduce<<<red_blocks, 256, 0, stream>>>(partials, kvt, split);

    la_phase2<<<NH * (L_L / 128), 256, 0, stream>>>(Q, kvt, out);
}

// Round 10
// 106.125 us; speedup vs baseline: 5.0199x; 3.6330x over previous
//
#include <hip/hip_runtime.h>
#include <hip/hip_bf16.h>
#include <cstddef>
#include <cstdint>

// Problem constants (fixed by the reference setup)
#define N_B   8
#define L_L   4096
#define S_S   4096
#define H_H   8
#define D_D   64
#define NH    64          // N_B * H_H
// KV_aug layout (d-major): rows 0..63 = KV[d][v] (stride 68, cols 64..67 pad),
// row 64 = K_sum[d] (indexed by d in cols 0..63). KVSZ floats per (n,h).
#define KVLD  68
#define KVSZ  (65 * KVLD)   // 4420

typedef const float __attribute__((address_space(1)))* gas_fp;
typedef float __attribute__((address_space(3)))* las_fp;

__device__ __forceinline__ float elu1(float x) {
    // elu(x)+1 : x>0 ? x+1 : exp(x)
    return x > 0.f ? x + 1.f : __expf(x);
}

// ---------------------------------------------------------------------------
// Phase 1 (v5): WAVE-PRIVATE pipeline, ZERO barriers in the main loop.
//  v2-v4 post-mortem: the single-barrier-per-tile structure made one giant
//  scheduling region; the scheduler clustered loads, RA spilled acc every
//  tile (~620MB scratch/launch) regardless of how many regs were "held"
//  (16 in v3, 8 in v4 -> same spill). Fighting the scheduler failed 3x.
//  v5: wave w computes s-rows w*16..w*16+15 AND stages exactly those rows:
//  K rows (tid>>2 = w*16..w*16+15 for wave w's tids) and V chunks (w*4+c).
//  All LDS traffic in the loop is wave-private -> no __syncthreads needed;
//  waves free-run, hiding HBM latency with TLP (16 waves/CU). V staged via
//  global_load_lds DMA (no regs, no elu needed); K load->elu->write with
//  v1-style short live ranges. Explicit vmcnt(0) (memory clobber) fences
//  the DMA before V's ds_reads. Barriers only after the loop (union alias).
//  Tile = 64 s-rows; ntiles = schunk/64.
// ---------------------------------------------------------------------------
__global__ __launch_bounds__(256, 3)
void la_phase1(const float* __restrict__ Kin, const float* __restrict__ Vin,
               float* __restrict__ partials, int split, int schunk)
{
    __shared__ union {
        struct { float K[64 * 64]; float V[64 * 64]; } st;   // 32 KB
        float acc[64 * 68];                                  // 17.3 KB
    } sm;
    __shared__ float sKsumP[4 * 64];     // per-wave ksum partials

    const int b     = blockIdx.x;
    const int nh    = b / split;
    const int chunk = b - nh * split;
    const int n     = nh >> 3;
    const int h     = nh & 7;
    const int s0    = chunk * schunk;

    const int tid  = threadIdx.x;
    const int w    = tid >> 6;
    const int lane = tid & 63;
    const int dg   = lane >> 3;   // d-group: d = dg*8 + i
    const int vg   = lane & 7;    // v-group: v = vg*8 + j

    float acc[8][8];
    #pragma unroll
    for (int i = 0; i < 8; ++i)
        #pragma unroll
        for (int j = 0; j < 8; ++j) acc[i][j] = 0.f;
    float ksum = 0.f;

    // K staging map: thread covers row tid>>2 (wave-private: rows w*16..w*16+15),
    // 64B at col (tid&3)*16
    const int ksr = tid >> 2;          // 0..63
    const int ksc = (tid & 3) * 16;    // 0,16,32,48
    const int kd  = lane;              // ksum d index (per-wave full coverage)

    // V DMA map: wave w issues chunks w*4+c (c=0..3); chunk ch covers
    // rows ch*4..ch*4+3 (lane l -> row ch*4+(l>>4), col (l&15)*4, 16B),
    // landing linearly at LDS float idx ch*256 + l*4 (wave-uniform base).
    const int vr = lane >> 4;          // 0..3
    const int vc = (lane & 15) * 4;

    const float* Kb = Kin + (size_t)n * S_S * (H_H * D_D) + h * D_D;
    const float* Vb = Vin + (size_t)n * S_S * (H_H * D_D) + h * D_D;

    const int ntiles = schunk >> 6;    // tiles of 64 s-rows

    for (int t = 0; t < ntiles; ++t) {
        const int srow = s0 + t * 64;

        // ---- V: async DMA into this wave's private rows (zero regs) ----
        #pragma unroll
        for (int c = 0; c < 4; ++c) {
            const int ch = w * 4 + c;
            __builtin_amdgcn_global_load_lds(
                (gas_fp)(Vb + (size_t)(srow + ch * 4 + vr) * (H_H * D_D) + vc),
                (las_fp)&sm.st.V[ch * 256], 16, 0, 0);
        }

        // ---- K: load -> elu -> write, wave-private rows, short live range ----
        #pragma unroll
        for (int p = 0; p < 4; ++p) {
            float4 kv = *(const float4*)(Kb + (size_t)(srow + ksr) * (H_H * D_D)
                                         + ksc + p * 4);
            kv.x = elu1(kv.x); kv.y = elu1(kv.y);
            kv.z = elu1(kv.z); kv.w = elu1(kv.w);
            *(float4*)&sm.st.K[ksr * 64 + ksc + p * 4] = kv;
        }

        // Fence: V-DMA arrival (wave-level; no block barrier — everything
        // this wave touches in the loop is wave-private). "memory" clobber
        // keeps the ds_writes above and the ds_reads below.
        asm volatile("s_waitcnt vmcnt(0)" ::: "memory");

        // ---- compute: wave w owns s-rows w*16 .. w*16+15 ----
        #pragma unroll 4
        for (int sl = 0; sl < 16; ++sl) {
            const int s = w * 16 + sl;
            const float4 k0 = *(const float4*)&sm.st.K[s * 64 + dg * 8];
            const float4 k1 = *(const float4*)&sm.st.K[s * 64 + dg * 8 + 4];
            const float4 v0 = *(const float4*)&sm.st.V[s * 64 + vg * 8];
            const float4 v1 = *(const float4*)&sm.st.V[s * 64 + vg * 8 + 4];
            const float kf[8] = {k0.x, k0.y, k0.z, k0.w, k1.x, k1.y, k1.z, k1.w};
            const float vf[8] = {v0.x, v0.y, v0.z, v0.w, v1.x, v1.y, v1.z, v1.w};
            #pragma unroll
            for (int i = 0; i < 8; ++i)
                #pragma unroll
                for (int j = 0; j < 8; ++j)
                    acc[i][j] = fmaf(kf[i], vf[j], acc[i][j]);
        }
        // K_sum partial over the same 16 rows this wave staged/consumed
        #pragma unroll
        for (int sl = 0; sl < 16; ++sl)
            ksum += sm.st.K[(w * 16 + sl) * 64 + kd];
    }
    __syncthreads();   // first block-wide sync: loop done; sm.acc (union) safe

    // cross-wave reduce of acc into sm.acc[d][v] (stride 68), sequential & exact
    for (int ww = 0; ww < 4; ++ww) {
        if (w == ww) {
            #pragma unroll
            for (int i = 0; i < 8; ++i) {
                float* p = &sm.acc[(dg * 8 + i) * 68 + vg * 8];
                if (ww == 0) {
                    *(float4*)p       = make_float4(acc[i][0], acc[i][1], acc[i][2], acc[i][3]);
                    *(float4*)(p + 4) = make_float4(acc[i][4], acc[i][5], acc[i][6], acc[i][7]);
                } else {
                    float4 a0 = *(const float4*)p;
                    float4 a1 = *(const float4*)(p + 4);
                    a0.x += acc[i][0]; a0.y += acc[i][1]; a0.z += acc[i][2]; a0.w += acc[i][3];
                    a1.x += acc[i][4]; a1.y += acc[i][5]; a1.z += acc[i][6]; a1.w += acc[i][7];
                    *(float4*)p       = a0;
                    *(float4*)(p + 4) = a1;
                }
            }
        }
        __syncthreads();
    }

    // ksum: deterministic 4-way reduce (one slot per (wave, d))
    sKsumP[w * 64 + kd] = ksum;
    __syncthreads();

    // write this block's partial KV_aug[65][68] d-major (row 64 = K_sum, pads 0)
    float* outp = partials + (size_t)b * KVSZ;
    for (int idx = tid; idx < KVSZ; idx += 256) {
        const int r = idx / KVLD;
        const int c = idx - r * KVLD;
        float val = 0.f;
        if (c < 64) {
            if (r < 64)
                val = sm.acc[idx];   // sm.acc is [d][v] stride 68 == same layout
            else
                val = sKsumP[c] + sKsumP[64 + c] + sKsumP[128 + c] + sKsumP[192 + c];
        }
        outp[idx] = val;
    }
}

// ---------------------------------------------------------------------------
// Reduce: sum the `split` partials per (n,h) -> kvt[nh][65][68]
// ---------------------------------------------------------------------------
__global__ __launch_bounds__(256)
void la_reduce(const float* __restrict__ partials, float* __restrict__ kvt, int split)
{
    const int idx = blockIdx.x * 256 + threadIdx.x;
    if (idx >= NH * KVSZ) return;
    const int nh  = idx / KVSZ;
    const int rem = idx - nh * KVSZ;
    const float* p = partials + (size_t)nh * split * KVSZ + rem;
    float s = 0.f;
    for (int c = 0; c < split; ++c) s += p[(size_t)c * KVSZ];
    kvt[idx] = s;
}

// ---------------------------------------------------------------------------
// Phase 2 (v5): register-tiled GEMM, Out[4096][65] = Qf[4096][64]*KV[64][65].
//  Per wave 64 rows x 32 cols, lane owns 8x4 tile; per k-chunk(4): 13
//  ds_read_b128 feed 160 FMAs; KV reused 8x, Q 4x in registers. Denominator
//  = KV row 64, accumulated per-lane for its own rows. Direct global stores.
//  (Round-6 measured ~20us ~= its 21us HBM floor -> unchanged.)
// ---------------------------------------------------------------------------
__global__ __launch_bounds__(256, 2)
void la_phase2(const float* __restrict__ Qin, const float* __restrict__ kvt,
               float* __restrict__ Out)
{
    __shared__ float sQ[128 * 68];   // 34.8 KB, row-major, stride 68
    __shared__ float sKV[KVSZ];      // 17.3 KB, [65][68] d-major

    const int b   = blockIdx.x;
    const int nh  = b >> 5;          // 32 l-chunks of 128 rows per (n,h)
    const int lc  = b & 31;
    const int n   = nh >> 3;
    const int h   = nh & 7;
    const int tid = threadIdx.x;
    const int w    = tid >> 6;
    const int lane = tid & 63;

    const float* Qc = Qin + (((size_t)n * L_L + (size_t)lc * 128) * H_H + h) * D_D;
    float*       Oc = Out + (((size_t)n * L_L + (size_t)lc * 128) * H_H + h) * D_D;

    // ---- stage KV_aug[65][68] into LDS (1105 float4, coalesced) ----
    {
        const float4* src = (const float4*)(kvt + (size_t)nh * KVSZ);
        float4*       dst = (float4*)sKV;
        #pragma unroll
        for (int it = 0; it < 4; ++it)
            dst[it * 256 + tid] = src[it * 256 + tid];
        if (tid < 81) dst[1024 + tid] = src[1024 + tid];
    }

    // ---- stage Q tile 128 rows x 64 cols (elu applied), stride 68 ----
    #pragma unroll
    for (int it = 0; it < 8; ++it) {
        const int slot = it * 256 + tid;   // 0..2047
        const int r    = slot >> 4;        // 0..127
        const int c4   = slot & 15;
        float4 v = *(const float4*)(Qc + (size_t)r * (H_H * D_D) + c4 * 4);
        v.x = elu1(v.x); v.y = elu1(v.y); v.z = elu1(v.z); v.w = elu1(v.w);
        *(float4*)&sQ[r * 68 + c4 * 4] = v;
    }
    __syncthreads();

    // ---- wave work assignment ----
    const int rt   = (w >> 1) * 64;        // row tile: 0 or 64
    const int wc   = w & 1;                // col half: 0 or 1
    const int rl   = lane & 7;             // row lane: rows rt + rl + 8j
    const int cg   = lane >> 3;            // col group
    const int ccol = wc * 32 + cg * 4;     // this lane's 4 output cols

    float acc[8][4];
    float den[8];
    #pragma unroll
    for (int j = 0; j < 8; ++j) {
        den[j] = 0.f;
        #pragma unroll
        for (int m = 0; m < 4; ++m) acc[j][m] = 0.f;
    }

    const int qbase = rt + rl;             // + 8j, stride-68 rows

    for (int kc = 0; kc < 16; ++kc) {
        // Q fragments: 8 rows x 4 k  (conflict-free b128: banks partition)
        float4 qv[8];
        #pragma unroll
        for (int j = 0; j < 8; ++j)
            qv[j] = *(const float4*)&sQ[(qbase + 8 * j) * 68 + kc * 4];
        // KV fragments: 4 k-rows x lane's 4 cols (conflict-free)
        const float4 kv0 = *(const float4*)&sKV[(kc * 4 + 0) * KVLD + ccol];
        const float4 kv1 = *(const float4*)&sKV[(kc * 4 + 1) * KVLD + ccol];
        const float4 kv2 = *(const float4*)&sKV[(kc * 4 + 2) * KVLD + ccol];
        const float4 kv3 = *(const float4*)&sKV[(kc * 4 + 3) * KVLD + ccol];
        // K_sum fragment: wave-uniform broadcast
        const float4 ks  = *(const float4*)&sKV[64 * KVLD + kc * 4];

        #pragma unroll
        for (int j = 0; j < 8; ++j) {
            const float q0 = qv[j].x, q1 = qv[j].y, q2 = qv[j].z, q3 = qv[j].w;
            den[j] = fmaf(q0, ks.x, den[j]);
            den[j] = fmaf(q1, ks.y, den[j]);
            den[j] = fmaf(q2, ks.z, den[j]);
            den[j] = fmaf(q3, ks.w, den[j]);
            acc[j][0] = fmaf(q0, kv0.x, acc[j][0]);
            acc[j][0] = fmaf(q1, kv1.x, acc[j][0]);
            acc[j][0] = fmaf(q2, kv2.x, acc[j][0]);
            acc[j][0] = fmaf(q3, kv3.x, acc[j][0]);
            acc[j][1] = fmaf(q0, kv0.y, acc[j][1]);
            acc[j][1] = fmaf(q1, kv1.y, acc[j][1]);
            acc[j][1] = fmaf(q2, kv2.y, acc[j][1]);
            acc[j][1] = fmaf(q3, kv3.y, acc[j][1]);
            acc[j][2] = fmaf(q0, kv0.z, acc[j][2]);
            acc[j][2] = fmaf(q1, kv1.z, acc[j][2]);
            acc[j][2] = fmaf(q2, kv2.z, acc[j][2]);
            acc[j][2] = fmaf(q3, kv3.z, acc[j][2]);
            acc[j][3] = fmaf(q0, kv0.w, acc[j][3]);
            acc[j][3] = fmaf(q1, kv1.w, acc[j][3]);
            acc[j][3] = fmaf(q2, kv2.w, acc[j][3]);
            acc[j][3] = fmaf(q3, kv3.w, acc[j][3]);
        }
    }

    // ---- epilogue: scale by 1/(den+eps), direct coalesced global stores ----
    #pragma unroll
    for (int j = 0; j < 8; ++j) {
        const float rz = 1.0f / (den[j] + 1e-6f);
        *(float4*)(Oc + (size_t)(qbase + 8 * j) * (H_H * D_D) + ccol) =
            make_float4(acc[j][0] * rz, acc[j][1] * rz,
                        acc[j][2] * rz, acc[j][3] * rz);
    }
}

// ---------------------------------------------------------------------------
extern "C" void kernel_launch(void* const* d_in, const int* in_sizes, int n_in,
                              void* d_out, int out_size, void* d_ws, size_t ws_size,
                              hipStream_t stream)
{
    const float* Q = (const float*)d_in[0];
    const float* K = (const float*)d_in[1];
    const float* V = (const float*)d_in[2];
    float* out = (float*)d_out;

    // ws layout: [ kvt: NH*KVSZ floats ][ partials: NH*split*KVSZ floats ]
    float* kvt = (float*)d_ws;
    const size_t kvt_bytes = (size_t)NH * KVSZ * sizeof(float);

    int split = 16;
    while (split > 1 &&
           kvt_bytes + (size_t)NH * split * KVSZ * sizeof(float) > ws_size)
        split >>= 1;
    float* partials = kvt + (size_t)NH * KVSZ;
    const int schunk = S_S / split;

    la_phase1<<<NH * split, 256, 0, stream>>>(K, V, partials, split, schunk);

    const int red_blocks = (NH * KVSZ + 255) / 256;   // 1105 exactly
    la_reduce<<<red_blocks, 256, 0, stream>>>(partials, kvt, split);

    la_phase2<<<NH * (L_L / 128), 256, 0, stream>>>(Q, kvt, out);
}